// Round 11
// baseline (69.229 us; speedup 1.0000x reference)
//
#include <hip/hip_runtime.h>

// MFMA-batched chunked-washout RNN — 1-wave/SIMD edition.
//
// R10 established: SIMD issue port saturated (VALUBusy ~112%), cost dominated
// by 32 poly-tanh/step. At saturation only instructions-per-SIMD matters.
// R11: (a) L1C 8->16, W1 24->32: 48 steps / 16 productive (3x redundancy,
// was 6x), 1024 waves = 1/SIMD -> per-SIMD issued work halves. W1=32 also
// restores the W>=32 washout accuracy floor (absmax 0.0039 measured in R7).
// (b) tanh trimmed 17->15 instrs: degree-4 Taylor for 2^f (rel err 6e-5),
// quadratic reciprocal init + single Newton (rel err 1.2e-4) — both well under
// the 5e-4 f16 state quantization noise.
// Structure otherwise identical to R10: rank-1 x/bias MFMAs (double-f16
// split), k-permuted weights so MFMA D-layout == next step's B-layout
// (D->B = 8 cvt_pkrtz, zero cross-lane ops), states f16 in registers.
// Phase 2: register-preloaded scalar hp scan (L2C=32, W2=64), unchanged.

namespace {
constexpr int T_LEN = 524288;
constexpr int H     = 32;
constexpr int L1C   = 16;                 // phase-1 chunk length
constexpr int W1    = 32;                 // phase-1 washout
constexpr int CPW   = 32;                 // chunks per wave
constexpr int GRID1 = T_LEN / (L1C * CPW);  // 1024 blocks x 64 threads
constexpr int L2C   = 32;                 // phase-2 chunk length
constexpr int NT2   = T_LEN / L2C;        // 16384 threads
}

typedef float  f32x16 __attribute__((ext_vector_type(16)));
typedef __fp16 f16x8  __attribute__((ext_vector_type(8)));

__device__ __forceinline__ unsigned pkh(float a, float b) {
  return __builtin_bit_cast(unsigned, __builtin_amdgcn_cvt_pkrtz(a, b));
}
__device__ __forceinline__ f16x8 mk8(unsigned a, unsigned b, unsigned c, unsigned d) {
  uint4 u = make_uint4(a, b, c, d);
  return __builtin_bit_cast(f16x8, u);
}
// Gather k-permuted fragment: cols {off+4hi..+3} and {off+8+4hi..+3}.
__device__ __forceinline__ f16x8 frag16(const float* p, int off, int hi4) {
  float4 a = *(const float4*)(p + off + hi4);
  float4 b = *(const float4*)(p + off + 8 + hi4);
  return mk8(pkh(a.x, a.y), pkh(a.z, a.w), pkh(b.x, b.y), pkh(b.z, b.w));
}
__device__ __forceinline__ f16x8 pack8(const float* t) {
  return mk8(pkh(t[0], t[1]), pkh(t[2], t[3]), pkh(t[4], t[5]), pkh(t[6], t[7]));
}

// tanh with zero transcendental instructions, ~15 VALU ops, abs err <= 2e-4.
//   tanh(x) = sign(x)*(2r - 1), r = 1/(1+2^z), z = -2|x|*log2(e)
//   2^f: degree-4 Taylor on [-0.5,0.5] (rel err 6e-5)
//   1/d, d in [1,2]: quadratic minimax init (rel err 1.1e-2) + 1 Newton -> 1.2e-4
__device__ __forceinline__ float poly_tanh(float x) {
  const float z  = __builtin_fabsf(x) * -2.8853900817779268f;
  const float nf = __builtin_rintf(z);                          // v_rndne_f32
  const float f  = z - nf;
  float p = 0.009618129107628477f;
  p = __builtin_fmaf(p, f, 0.05550410866482158f);
  p = __builtin_fmaf(p, f, 0.2402265069591007f);
  p = __builtin_fmaf(p, f, 0.6931471805599453f);
  p = __builtin_fmaf(p, f, 1.0f);
  const float e = __builtin_amdgcn_ldexpf(p, (int)nf);          // 2^z in [0,1]
  const float d = e + 1.0f;                                     // [1,2]
  float r = __builtin_fmaf(0.31275f, d, -1.42315f);             // quadratic init
  r = __builtin_fmaf(r, d, 2.10079f);
  r = __builtin_fmaf(r, __builtin_fmaf(-d, r, 1.0f), r);        // Newton
  const float th = __builtin_fmaf(2.0f, r, -1.0f);              // tanh(|x|)
  return __builtin_copysignf(th, x);
}

// exp-based tanh (phase 2 only; off the hot path)
__device__ __forceinline__ float fast_tanh(float x) {
  float e = __expf(2.0f * x);
  return 1.0f - 2.0f / (e + 1.0f);
}

#define MFMA(A, B, C) __builtin_amdgcn_mfma_f32_32x32x16_f16((A), (B), (C), 0, 0, 0)

__global__ __launch_bounds__(64)
void rnn_phase1(
    const float* __restrict__ x,
    const float* __restrict__ x_lb,
    const float* __restrict__ x_ub,
    const float* __restrict__ W_ih0,
    const float* __restrict__ W_hh0,
    const float* __restrict__ b_ih0,
    const float* __restrict__ b_hh0,
    const float* __restrict__ W_ih1,
    const float* __restrict__ W_hh1,
    const float* __restrict__ b_ih1,
    const float* __restrict__ b_hh1,
    const float* __restrict__ Wp_ih,
    const float* __restrict__ prev_h0,
    float* __restrict__ wsP)
{
  const int lane = threadIdx.x;            // block = 1 wave
  const int c    = lane & 31;              // chunk column / weight row
  const int hi   = lane >> 5;              // wave half
  const int hi4  = hi * 4;
  const int w    = blockIdx.x;
  const int g    = w * CPW + c;            // global chunk id

  // ---- k-permuted weight fragments (24 VGPRs) ----
  const f16x8 A00a = frag16(&W_hh0[c * H],  0, hi4);
  const f16x8 A00b = frag16(&W_hh0[c * H], 16, hi4);
  const f16x8 A10a = frag16(&W_ih1[c * H],  0, hi4);
  const f16x8 A10b = frag16(&W_ih1[c * H], 16, hi4);
  const f16x8 A11a = frag16(&W_hh1[c * H],  0, hi4);
  const f16x8 A11b = frag16(&W_hh1[c * H], 16, hi4);

  // ---- rank-1 x/bias fragments, double-f16 split (f32-exact path) ----
  const float lb  = x_lb[0];
  const float ub  = x_ub[0];
  const float inv = 1.0f / (ub - lb);
  const float wih = W_ih0[c];
  const float wxm = wih * inv;
  const float b0m = b_ih0[c] + b_hh0[c] - wih * lb * inv;
  const float b1m = b_ih1[c] + b_hh1[c];
  const float wxl = wxm - (float)(__fp16)wxm;
  const float b0l = b0m - (float)(__fp16)b0m;
  const float b1l = b1m - (float)(__fp16)b1m;
  // slots: 0:wxh*xh 1:b0h*1 2:wxh*xl 3:wxl*xh 4:b0l*1
  const f16x8 A0x = hi ? mk8(0,0,0,0)
                       : mk8(pkh(wxm, b0m), pkh(wxm, wxl), pkh(b0l, 0.f), 0);
  // slots: 1:b1h*1 4:b1l*1
  const f16x8 A1x = hi ? mk8(0,0,0,0)
                       : mk8(pkh(0.f, b1m), 0, pkh(b1l, 0.f), 0);
  const unsigned bx2 = hi ? 0u : pkh(1.0f, 0.0f);   // Bx slot4 = 1

  // ---- per-(reg,half) Wp row constants (D layout, f32) ----
  float wpd[16];
#pragma unroll
  for (int j = 0; j < 16; ++j)
    wpd[j] = Wp_ih[(j & 3) + 8 * (j >> 2) + hi4];

  // ---- states in packed B layout (zero-washout init) ----
  f16x8 H0B0 = mk8(0,0,0,0), H0B1 = mk8(0,0,0,0);
  f16x8 H1B0 = mk8(0,0,0,0), H1B1 = mk8(0,0,0,0);

  const int tbase = g * L1C - W1;          // global t at step 0
  const f32x16 Z16 = {};

  auto loadx4 = [&](int idx) -> float4 {   // idx 4-aligned by construction
    idx = min(max(idx, 0), T_LEN - 4);
    return *(const float4*)&x[idx];
  };

  auto stepf = [&](float xc) -> float {
    // Bx: slots {xh, 1, xl, xh, 1} (hi=0 lanes only)
    const float xl = xc - (float)(__fp16)xc;
    const unsigned u0 = hi ? 0u : pkh(xc, 1.0f);
    const unsigned u1 = hi ? 0u : pkh(xl, xc);
    const f16x8 Bx = mk8(u0, u1, bx2, 0);

    // layer 0: D = W00 @ h0 + (wx*x + b0)
    f32x16 acc = MFMA(A0x, Bx, Z16);
    acc = MFMA(A00a, H0B0, acc);
    acc = MFMA(A00b, H0B1, acc);
    float t0[16];
#pragma unroll
    for (int j = 0; j < 16; ++j) t0[j] = poly_tanh(acc[j]);
    H0B0 = pack8(t0);                      // D IS next B (k-permuted weights)
    H0B1 = pack8(t0 + 8);

    // layer 1: D = W10 @ h0new + W11 @ h1 + b1
    f32x16 a1 = MFMA(A1x, Bx, Z16);
    a1 = MFMA(A10a, H0B0, a1);
    a1 = MFMA(A10b, H0B1, a1);
    a1 = MFMA(A11a, H1B0, a1);
    a1 = MFMA(A11b, H1B1, a1);
    float t1[16];
#pragma unroll
    for (int j = 0; j < 16; ++j) t1[j] = poly_tanh(a1[j]);
    H1B0 = pack8(t1);
    H1B1 = pack8(t1 + 8);

    // P partial: this half's 16 rows of Wp_ih . h1
    float p0 = 0.f, p1 = 0.f, p2 = 0.f, p3 = 0.f;
#pragma unroll
    for (int j = 0; j < 16; j += 4) {
      p0 = __builtin_fmaf(wpd[j + 0], t1[j + 0], p0);
      p1 = __builtin_fmaf(wpd[j + 1], t1[j + 1], p1);
      p2 = __builtin_fmaf(wpd[j + 2], t1[j + 2], p2);
      p3 = __builtin_fmaf(wpd[j + 3], t1[j + 3], p3);
    }
    float ps = (p0 + p1) + (p2 + p3);
    ps += __shfl_xor(ps, 32);              // combine halves (DCE'd in warmup)
    return ps;
  };

  // ---- warmup: 32 steps (P result unused -> dot/shfl dead-code-eliminated) ----
  float4 xv = loadx4(tbase);
#pragma unroll 2
  for (int sq = 0; sq < W1 / 4; ++sq) {
    float4 xn = loadx4(tbase + 4 * (sq + 1));
    stepf(xv.x); stepf(xv.y); stepf(xv.z); stepf(xv.w);
    xv = xn;
  }

  // ---- chunk 0: exact initial state right before global t = 0 ----
  if (w == 0 && c == 0) {
    H0B0 = frag16(prev_h0,      0, hi4);
    H0B1 = frag16(prev_h0,     16, hi4);
    H1B0 = frag16(prev_h0 + H,  0, hi4);
    H1B1 = frag16(prev_h0 + H, 16, hi4);
  }

  // ---- productive: 16 steps, compile-time output indices ----
  float4 xv2 = loadx4(tbase + W1 + 4);
  float4 xv3 = loadx4(tbase + W1 + 8);
  float4 xv4 = loadx4(tbase + W1 + 12);
  float4 po0, po1, po2, po3;
  po0.x = stepf(xv.x);  po0.y = stepf(xv.y);
  po0.z = stepf(xv.z);  po0.w = stepf(xv.w);
  po1.x = stepf(xv2.x); po1.y = stepf(xv2.y);
  po1.z = stepf(xv2.z); po1.w = stepf(xv2.w);
  po2.x = stepf(xv3.x); po2.y = stepf(xv3.y);
  po2.z = stepf(xv3.z); po2.w = stepf(xv3.w);
  po3.x = stepf(xv4.x); po3.y = stepf(xv4.y);
  po3.z = stepf(xv4.z); po3.w = stepf(xv4.w);

  if (lane < 32) {                         // ps uniform across halves
    float* dst = wsP + (size_t)g * L1C;
    *(float4*)(dst +  0) = po0;
    *(float4*)(dst +  4) = po1;
    *(float4*)(dst +  8) = po2;
    *(float4*)(dst + 12) = po3;
  }
}

__global__ __launch_bounds__(64) void rnn_phase2(
    const float* __restrict__ wsP,
    const float* __restrict__ Wp_hh,
    const float* __restrict__ bp_ih,
    const float* __restrict__ bp_hh,
    const float* __restrict__ post_h0,
    float* __restrict__ out)
{
  const int i = blockIdx.x * 64 + threadIdx.x;    // 0..NT2-1
  const float wpp = Wp_hh[0];
  const float bpc = bp_ih[0] + bp_hh[0];
  const int start = i * L2C;

  // Preload whole window [start-64, start+32) as 24 independent float4s,
  // pre-biased by bpc. Negative t clamps to 0 (those slots are unused).
  float4 v[24];
#pragma unroll
  for (int k = 0; k < 24; ++k) {
    int t = start - 64 + 4 * k;
    t = t < 0 ? 0 : t;
    float4 u = *(const float4*)&wsP[t];
    u.x += bpc; u.y += bpc; u.z += bpc; u.w += bpc;
    v[k] = u;
  }

  float hp = 0.0f;
  if (i >= 2) {                            // washout [start-64, start-32)
#pragma unroll
    for (int k = 0; k < 8; ++k) {
      hp = fast_tanh(__builtin_fmaf(wpp, hp, v[k].x));
      hp = fast_tanh(__builtin_fmaf(wpp, hp, v[k].y));
      hp = fast_tanh(__builtin_fmaf(wpp, hp, v[k].z));
      hp = fast_tanh(__builtin_fmaf(wpp, hp, v[k].w));
    }
  }
  if (i >= 1) {                            // washout [start-32, start)
#pragma unroll
    for (int k = 8; k < 16; ++k) {
      hp = fast_tanh(__builtin_fmaf(wpp, hp, v[k].x));
      hp = fast_tanh(__builtin_fmaf(wpp, hp, v[k].y));
      hp = fast_tanh(__builtin_fmaf(wpp, hp, v[k].z));
      hp = fast_tanh(__builtin_fmaf(wpp, hp, v[k].w));
    }
  }
  if (i == 0) hp = post_h0[0];             // exact init at t = 0

#pragma unroll
  for (int k = 16; k < 24; ++k) {          // productive [start, start+32)
    float4 o;
    o.x = hp = fast_tanh(__builtin_fmaf(wpp, hp, v[k].x));
    o.y = hp = fast_tanh(__builtin_fmaf(wpp, hp, v[k].y));
    o.z = hp = fast_tanh(__builtin_fmaf(wpp, hp, v[k].z));
    o.w = hp = fast_tanh(__builtin_fmaf(wpp, hp, v[k].w));
    *(float4*)&out[start + 4 * (k - 16)] = o;
  }
}

extern "C" void kernel_launch(void* const* d_in, const int* in_sizes, int n_in,
                              void* d_out, int out_size, void* d_ws, size_t ws_size,
                              hipStream_t stream) {
  const float* x       = (const float*)d_in[0];
  const float* x_lb    = (const float*)d_in[1];
  const float* x_ub    = (const float*)d_in[2];
  const float* W_ih0   = (const float*)d_in[3];
  const float* W_hh0   = (const float*)d_in[4];
  const float* b_ih0   = (const float*)d_in[5];
  const float* b_hh0   = (const float*)d_in[6];
  const float* W_ih1   = (const float*)d_in[7];
  const float* W_hh1   = (const float*)d_in[8];
  const float* b_ih1   = (const float*)d_in[9];
  const float* b_hh1   = (const float*)d_in[10];
  const float* Wp_ih   = (const float*)d_in[11];
  const float* Wp_hh   = (const float*)d_in[12];
  const float* bp_ih   = (const float*)d_in[13];
  const float* bp_hh   = (const float*)d_in[14];
  const float* prev_h0 = (const float*)d_in[15];
  const float* post_h0 = (const float*)d_in[16];
  float* out = (float*)d_out;
  float* wsP = (float*)d_ws;               // 2 MB of P values

  rnn_phase1<<<GRID1, 64, 0, stream>>>(
      x, x_lb, x_ub, W_ih0, W_hh0, b_ih0, b_hh0,
      W_ih1, W_hh1, b_ih1, b_hh1, Wp_ih, prev_h0, wsP);
  rnn_phase2<<<NT2 / 64, 64, 0, stream>>>(wsP, Wp_hh, bp_ih, bp_hh, post_h0, out);
}